// Round 13
// baseline (70.793 us; speedup 1.0000x reference)
//
#include <hip/hip_runtime.h>
#include <hip/hip_bf16.h>

// Problem constants: M=100000 points, K=27 offsets, Cin=Cout=64.
// R13: R12 layouts (single-segment 64B row gathers, pair-packed 1KB W frags)
// + B amortized over 64 rows/wave (4 row-tiles). Block = 128 threads (2
// waves) covering 128 rows; grid stays 782 for load balance. Per wave-ko:
// 4 A-loads + 4 B-loads for 64 rows (was 2+4 for 32).
#define NPTS 100000
#define KOFF 27
#define KPAD 28          // padded K: tile 27 = zero weights + zero-row gathers
#define NCH  64

typedef __attribute__((ext_vector_type(4))) float f32x4;
typedef __attribute__((ext_vector_type(4))) unsigned int u32x4;
typedef __attribute__((ext_vector_type(2))) long long2_t;   // 16B, .x/.y = i64

// feats fp32 (M x 64) -> fp8 e4m3 swizzled rows. Row byte p = lk*16 + h*8 + j
// holds channel c = h*32 + lk*8 + j. One thread per (m, lk) 16B block.
// Row NPTS all-zero (gather target for invalid rulebook entries).
__global__ void convert_feats_kernel(const float* __restrict__ feats,
                                     unsigned char* __restrict__ f8) {
  int tid = blockIdx.x * 256 + threadIdx.x;
  const int total = (NPTS + 1) * 4;
  if (tid >= total) return;
  const int m  = tid >> 2;
  const int lk = tid & 3;
  unsigned int w0 = 0, w1 = 0, w2 = 0, w3 = 0;
  if (m < NPTS) {
    const float* r = feats + (size_t)m * NCH + lk * 8;
    const float4 a = *reinterpret_cast<const float4*>(r);          // c0 j0-3
    const float4 b = *reinterpret_cast<const float4*>(r + 4);      // c0 j4-7
    const float4 c = *reinterpret_cast<const float4*>(r + 32);     // c1 j0-3
    const float4 d = *reinterpret_cast<const float4*>(r + 36);     // c1 j4-7
    int p;
    p = __builtin_amdgcn_cvt_pk_fp8_f32(a.x, a.y, 0, false);
    p = __builtin_amdgcn_cvt_pk_fp8_f32(a.z, a.w, p, true);  w0 = (unsigned)p;
    p = __builtin_amdgcn_cvt_pk_fp8_f32(b.x, b.y, 0, false);
    p = __builtin_amdgcn_cvt_pk_fp8_f32(b.z, b.w, p, true);  w1 = (unsigned)p;
    p = __builtin_amdgcn_cvt_pk_fp8_f32(c.x, c.y, 0, false);
    p = __builtin_amdgcn_cvt_pk_fp8_f32(c.z, c.w, p, true);  w2 = (unsigned)p;
    p = __builtin_amdgcn_cvt_pk_fp8_f32(d.x, d.y, 0, false);
    p = __builtin_amdgcn_cvt_pk_fp8_f32(d.z, d.w, p, true);  w3 = (unsigned)p;
  }
  *reinterpret_cast<u32x4*>(f8 + (size_t)m * 64 + lk * 16) = u32x4{w0, w1, w2, w3};
}

// weight fp32 [k][cin][cout] -> fp8 pair-packed fragments: block (ko, nt) is
// 1KB; lane L's 16B at L*16; byte h*8+j holds W[ko][h*32 + 8*(L>>4) + j][
// nt*16 + (L&15)]. One 16B load/lane yields both cin-chunk fragments.
__global__ void convert_weight_kernel(const float* __restrict__ w,
                                      unsigned char* __restrict__ wt) {
  int tid = blockIdx.x * 256 + threadIdx.x;
  if (tid >= KPAD * NCH * NCH) return;
  int ko  = tid >> 12;
  int rem = tid & 4095;
  int c   = rem >> 6;
  int o   = rem & 63;
  float val = (ko < KOFF) ? w[(size_t)ko * 4096 + c * 64 + o] : 0.0f;
  int p8 = __builtin_amdgcn_cvt_pk_fp8_f32(val, 0.0f, 0, false);
  const int h  = c >> 5;
  const int kk = c & 31;
  const int L  = ((kk >> 3) << 4) | (o & 15);
  int dst = ((ko * 4) + (o >> 4)) * 1024 + L * 16 + h * 8 + (kk & 7);
  wt[dst] = (unsigned char)(p8 & 0xff);
}

// Main kernel: block = 128 rows, 2 waves (128 thr); wave owns 64 rows
// (4 row-tiles of 16) x 64 cout x 28 kos. Per ko: 4 A-loads (16B/lane, one
// 64B segment per row) + 4 B-loads (1KB contiguous) + 32 MFMAs.
// R12 consume-immediate schedule.
__global__ __launch_bounds__(128, 2)
void spconv_kernel(const unsigned char* __restrict__ f8,       // (NPTS+1)x64 fp8 swz
                   const int* __restrict__ rulebook,           // NPTS x 27 int32
                   const unsigned char* __restrict__ wl,       // pair-packed fp8 W
                   const float* __restrict__ feats,            // NPTS x 64 fp32
                   const float* __restrict__ bias,             // 64 fp32
                   float* __restrict__ out) {                  // NPTS x 64 fp32
  __shared__ int s_off[128][KPAD];   // BYTE offsets into f8 (idx*64)
  __shared__ int s_cnt[128];

  const int tid = threadIdx.x;
  const int m0  = blockIdx.x * 128;

  if (tid < 128) s_cnt[tid] = 0;
  __syncthreads();

  for (int f = tid; f < 128 * KPAD; f += 128) {
    int r = f / KPAD, k = f - r * KPAD;
    int m = m0 + r;
    int off = NPTS * 64;
    if (m < NPTS && k < KOFF) {
      int v = rulebook[(size_t)m * KOFF + k];
      if (v >= 0) { off = v * 64; atomicAdd(&s_cnt[r], 1); }
    }
    s_off[r][k] = off;
  }
  __syncthreads();

  const int wave = tid >> 6;           // 0..1
  const int lane = tid & 63;
  const int lr   = lane & 15;
  const int lk   = lane >> 4;
  const int lk16 = lk * 16;            // byte offset of lane's 16B within row
  const int row0 = wave * 64 + lr;
  const int row1 = wave * 64 + 16 + lr;
  const int row2 = wave * 64 + 32 + lr;
  const int row3 = wave * 64 + 48 + lr;

  const char* fbase = (const char*)f8;
  const char* wlane = (const char*)wl + lane * 16;

  f32x4 acc0[4] = {f32x4{0,0,0,0}, f32x4{0,0,0,0}, f32x4{0,0,0,0}, f32x4{0,0,0,0}};
  f32x4 acc1[4] = {f32x4{0,0,0,0}, f32x4{0,0,0,0}, f32x4{0,0,0,0}, f32x4{0,0,0,0}};
  f32x4 acc2[4] = {f32x4{0,0,0,0}, f32x4{0,0,0,0}, f32x4{0,0,0,0}, f32x4{0,0,0,0}};
  f32x4 acc3[4] = {f32x4{0,0,0,0}, f32x4{0,0,0,0}, f32x4{0,0,0,0}, f32x4{0,0,0,0}};

  // A: 2 ko-sets x 4 row-tiles, 16B each (.x=chunk0, .y=chunk1).
  long2_t A0r0, A0r1, A0r2, A0r3;
  long2_t A1r0, A1r1, A1r2, A1r3;
  // B: single set, 4 pair-packed frags (nt 0..3), reloaded after consumption.
  long2_t B0, B1, B2, B3;

#define LOADA(R0, R1, R2, R3, KO) {                                           \
    R0 = *reinterpret_cast<const long2_t*>(fbase + (size_t)(unsigned)s_off[row0][(KO)] + lk16); \
    R1 = *reinterpret_cast<const long2_t*>(fbase + (size_t)(unsigned)s_off[row1][(KO)] + lk16); \
    R2 = *reinterpret_cast<const long2_t*>(fbase + (size_t)(unsigned)s_off[row2][(KO)] + lk16); \
    R3 = *reinterpret_cast<const long2_t*>(fbase + (size_t)(unsigned)s_off[row3][(KO)] + lk16); \
  }

#define LOADB(KO) {                                                           \
    const char* wb_ = wlane + (size_t)(KO) * 4096;                            \
    B0 = *reinterpret_cast<const long2_t*>(wb_ + 0 * 1024);                   \
    B1 = *reinterpret_cast<const long2_t*>(wb_ + 1 * 1024);                   \
    B2 = *reinterpret_cast<const long2_t*>(wb_ + 2 * 1024);                   \
    B3 = *reinterpret_cast<const long2_t*>(wb_ + 3 * 1024);                   \
  }

#define MFMA_RT(ACC, R) {                                                     \
    ACC[0] = __builtin_amdgcn_mfma_f32_16x16x32_fp8_fp8(R.x, B0.x, ACC[0],0,0,0);\
    ACC[0] = __builtin_amdgcn_mfma_f32_16x16x32_fp8_fp8(R.y, B0.y, ACC[0],0,0,0);\
    ACC[1] = __builtin_amdgcn_mfma_f32_16x16x32_fp8_fp8(R.x, B1.x, ACC[1],0,0,0);\
    ACC[1] = __builtin_amdgcn_mfma_f32_16x16x32_fp8_fp8(R.y, B1.y, ACC[1],0,0,0);\
    ACC[2] = __builtin_amdgcn_mfma_f32_16x16x32_fp8_fp8(R.x, B2.x, ACC[2],0,0,0);\
    ACC[2] = __builtin_amdgcn_mfma_f32_16x16x32_fp8_fp8(R.y, B2.y, ACC[2],0,0,0);\
    ACC[3] = __builtin_amdgcn_mfma_f32_16x16x32_fp8_fp8(R.x, B3.x, ACC[3],0,0,0);\
    ACC[3] = __builtin_amdgcn_mfma_f32_16x16x32_fp8_fp8(R.y, B3.y, ACC[3],0,0,0);\
  }

#define MFMA_STEP(R0, R1, R2, R3) {                                           \
    MFMA_RT(acc0, R0) MFMA_RT(acc1, R1) MFMA_RT(acc2, R2) MFMA_RT(acc3, R3)   \
  }

  // Prologue: A(0), A(1), B(0) in flight.
  LOADA(A0r0, A0r1, A0r2, A0r3, 0)
  LOADA(A1r0, A1r1, A1r2, A1r3, 1)
  LOADB(0)

  #pragma unroll 1
  for (int kk = 0; kk < KPAD / 2; ++kk) {
    const int ko = kk * 2;
    MFMA_STEP(A0r0, A0r1, A0r2, A0r3)             // consumes A(ko), B(ko)
    LOADB(ko + 1)
    if (ko + 2 < KPAD) LOADA(A0r0, A0r1, A0r2, A0r3, ko + 2)
    MFMA_STEP(A1r0, A1r1, A1r2, A1r3)             // consumes A(ko+1), B(ko+1)
    if (ko + 2 < KPAD) LOADB(ko + 2)
    if (ko + 3 < KPAD) LOADA(A1r0, A1r1, A1r2, A1r3, ko + 3)
  }
#undef LOADA
#undef LOADB
#undef MFMA_RT
#undef MFMA_STEP

  // Epilogue: /denom + bias + residual.
  #pragma unroll
  for (int rt = 0; rt < 4; ++rt) {
    const f32x4* acc = (rt == 0) ? acc0 : (rt == 1) ? acc1 : (rt == 2) ? acc2 : acc3;
    #pragma unroll
    for (int nt = 0; nt < 4; ++nt) {
      const int col = nt * 16 + lr;
      const float b = bias[col];
      #pragma unroll
      for (int i = 0; i < 4; ++i) {
        const int rl = wave * 64 + rt * 16 + lk * 4 + i;
        const int m  = m0 + rl;
        if (m < NPTS) {
          const float denom = (float)max(s_cnt[rl], 1);
          out[(size_t)m * NCH + col] =
              acc[nt][i] / denom + b + feats[(size_t)m * NCH + col];
        }
      }
    }
  }
}

extern "C" void kernel_launch(void* const* d_in, const int* in_sizes, int n_in,
                              void* d_out, int out_size, void* d_ws, size_t ws_size,
                              hipStream_t stream) {
  const float* feats    = (const float*)d_in[0];
  const int*   rulebook = (const int*)d_in[1];
  const float* weight   = (const float*)d_in[2];
  const float* bias     = (const float*)d_in[3];
  float* out = (float*)d_out;

  // Workspace: [0, ~6.4MB) feats fp8 swizzled rows; then weights fp8 (112KB).
  unsigned char* f8 = (unsigned char*)d_ws;
  const size_t f8_bytes = (size_t)(NPTS + 1) * NCH;          // 6,400,064
  const size_t wt_off   = (f8_bytes + 1023) & ~(size_t)1023;
  unsigned char* wl = (unsigned char*)((char*)d_ws + wt_off);

  {
    const int total = (NPTS + 1) * 4;                        // 16B blocks
    convert_feats_kernel<<<(total + 255) / 256, 256, 0, stream>>>(feats, f8);
  }
  {
    const int n = KPAD * NCH * NCH;
    convert_weight_kernel<<<(n + 255) / 256, 256, 0, stream>>>(weight, wl);
  }
  {
    const int nblk = (NPTS + 127) / 128;   // 782
    spconv_kernel<<<nblk, 128, 0, stream>>>(f8, rulebook, wl, feats, bias, out);
  }
}